// Round 1
// baseline (494.373 us; speedup 1.0000x reference)
//
#include <hip/hip_runtime.h>

// LinearAttention: B=4, H=16, S=8192, D=64, fp32 in/out.
// out[bh,s,e] = (relu(q[s])·kv)[e] / max(relu(q[s])·ksum, 1e-6)
// kv[d][e] = sum_s relu(k[s][d]) * v[s][e];  ksum[d] = sum_s relu(k[s][d])

#define NBH 64
#define SEQ 8192
#define DIM 64
#define NSPLIT 16                       // S-splits per head in pass 1
#define ROWS_A (SEQ / NSPLIT)           // 512 rows per block
#define TILE_A 32                       // rows staged per iteration
#define KV_STRIDE (DIM * DIM + DIM)     // 4160 floats per head in ws

// ---------------- Pass 1: partial kv + ksum per (bh, chunk) ----------------
__global__ __launch_bounds__(256) void la_kv(const float* __restrict__ K,
                                             const float* __restrict__ V,
                                             float* __restrict__ ws) {
    const int t = threadIdx.x;
    const int bh = blockIdx.x >> 4;
    const int chunk = blockIdx.x & (NSPLIT - 1);
    const int td = t >> 4;   // d-group 0..15
    const int te = t & 15;   // e-group 0..15

    __shared__ float sk[TILE_A * DIM];
    __shared__ float sv[TILE_A * DIM];

    float acc[4][4] = {};
    float ks[4] = {0.f, 0.f, 0.f, 0.f};

    const int base = bh * (SEQ * DIM) + chunk * (ROWS_A * DIM);
    const float4* K4 = reinterpret_cast<const float4*>(K + base);
    const float4* V4 = reinterpret_cast<const float4*>(V + base);

    for (int tile = 0; tile < ROWS_A / TILE_A; ++tile) {
        const int f0 = tile * (TILE_A * DIM / 4);  // 512 float4 per tile
        float4 ka = K4[f0 + t];
        float4 kb = K4[f0 + t + 256];
        float4 va = V4[f0 + t];
        float4 vb = V4[f0 + t + 256];
        ka.x = fmaxf(ka.x, 0.f); ka.y = fmaxf(ka.y, 0.f);
        ka.z = fmaxf(ka.z, 0.f); ka.w = fmaxf(ka.w, 0.f);
        kb.x = fmaxf(kb.x, 0.f); kb.y = fmaxf(kb.y, 0.f);
        kb.z = fmaxf(kb.z, 0.f); kb.w = fmaxf(kb.w, 0.f);
        // ksum rides the staging loads: both chunks of this thread hit d0 = te*4
        ks[0] += ka.x + kb.x; ks[1] += ka.y + kb.y;
        ks[2] += ka.z + kb.z; ks[3] += ka.w + kb.w;
        __syncthreads();   // previous tile's LDS reads done
        *reinterpret_cast<float4*>(&sk[t * 4]) = ka;
        *reinterpret_cast<float4*>(&sk[1024 + t * 4]) = kb;
        *reinterpret_cast<float4*>(&sv[t * 4]) = va;
        *reinterpret_cast<float4*>(&sv[1024 + t * 4]) = vb;
        __syncthreads();
        #pragma unroll 8
        for (int ss = 0; ss < TILE_A; ++ss) {
            // k read: 4 distinct addrs/wave (16-way bcast); v: 16 distinct (2/bank, free)
            float4 kk = *reinterpret_cast<const float4*>(&sk[ss * DIM + td * 4]);
            float4 vv = *reinterpret_cast<const float4*>(&sv[ss * DIM + te * 4]);
            acc[0][0] = fmaf(kk.x, vv.x, acc[0][0]);
            acc[0][1] = fmaf(kk.x, vv.y, acc[0][1]);
            acc[0][2] = fmaf(kk.x, vv.z, acc[0][2]);
            acc[0][3] = fmaf(kk.x, vv.w, acc[0][3]);
            acc[1][0] = fmaf(kk.y, vv.x, acc[1][0]);
            acc[1][1] = fmaf(kk.y, vv.y, acc[1][1]);
            acc[1][2] = fmaf(kk.y, vv.z, acc[1][2]);
            acc[1][3] = fmaf(kk.y, vv.w, acc[1][3]);
            acc[2][0] = fmaf(kk.z, vv.x, acc[2][0]);
            acc[2][1] = fmaf(kk.z, vv.y, acc[2][1]);
            acc[2][2] = fmaf(kk.z, vv.z, acc[2][2]);
            acc[2][3] = fmaf(kk.z, vv.w, acc[2][3]);
            acc[3][0] = fmaf(kk.w, vv.x, acc[3][0]);
            acc[3][1] = fmaf(kk.w, vv.y, acc[3][1]);
            acc[3][2] = fmaf(kk.w, vv.z, acc[3][2]);
            acc[3][3] = fmaf(kk.w, vv.w, acc[3][3]);
        }
    }

    float* w = ws + bh * KV_STRIDE;
    #pragma unroll
    for (int i = 0; i < 4; ++i)
        #pragma unroll
        for (int j = 0; j < 4; ++j)
            atomicAdd(&w[(td * 4 + i) * DIM + te * 4 + j], acc[i][j]);

    // ksum: reduce the 4 td-groups of this wave, then one atomic per (wave, te)
    #pragma unroll
    for (int c = 0; c < 4; ++c) {
        ks[c] += __shfl_xor(ks[c], 16);
        ks[c] += __shfl_xor(ks[c], 32);
    }
    if ((t & 48) == 0) {
        #pragma unroll
        for (int c = 0; c < 4; ++c)
            atomicAdd(&w[DIM * DIM + te * 4 + c], ks[c]);
    }
}

// ---------------- Pass 2: out = (relu(q)·kv) / max(relu(q)·ksum, 1e-6) -----
#define TILES_B 8
#define TILE_B 64
#define QPAD 68   // keeps float4 alignment, 2-way max on scalar column reads

__global__ __launch_bounds__(256) void la_out(const float* __restrict__ Q,
                                              const float* __restrict__ ws,
                                              float* __restrict__ out) {
    const int t = threadIdx.x;
    const int bh = blockIdx.x >> 4;
    const int chunk = blockIdx.x & 15;
    const int sr = t >> 2;   // row in tile 0..63
    const int te = t & 3;    // e-quad 0..3

    __shared__ float skv[DIM * DIM];     // 16 KB
    __shared__ float sks[DIM];
    __shared__ float sq[TILE_B * QPAD];  // 17 KB
    __shared__ float sinv[TILE_B];

    const float* w = ws + bh * KV_STRIDE;
    #pragma unroll
    for (int i = 0; i < 4; ++i)
        *reinterpret_cast<float4*>(&skv[(t + i * 256) * 4]) =
            *reinterpret_cast<const float4*>(&w[(t + i * 256) * 4]);
    if (t < 16)
        *reinterpret_cast<float4*>(&sks[t * 4]) =
            *reinterpret_cast<const float4*>(&w[DIM * DIM + t * 4]);

    const int rowbase0 = chunk * (TILES_B * TILE_B);
    const float* Qb = Q + bh * (SEQ * DIM);
    float* Ob = out + bh * (SEQ * DIM);

    for (int tile = 0; tile < TILES_B; ++tile) {
        const int rb = rowbase0 + tile * TILE_B;
        __syncthreads();   // prev tile's sq/sinv reads done (1st iter: kv staged)
        #pragma unroll
        for (int i = 0; i < 4; ++i) {
            const int idx = t + i * 256;                 // float4 index in tile
            float4 q4 = *reinterpret_cast<const float4*>(&Qb[rb * DIM + idx * 4]);
            q4.x = fmaxf(q4.x, 0.f); q4.y = fmaxf(q4.y, 0.f);
            q4.z = fmaxf(q4.z, 0.f); q4.w = fmaxf(q4.w, 0.f);
            const int row = idx >> 4;
            const int d0 = (idx & 15) * 4;
            *reinterpret_cast<float4*>(&sq[row * QPAD + d0]) = q4;
        }
        __syncthreads();
        if (t < TILE_B) {   // one thread per row: inv-normalizer
            float n = 0.f;
            #pragma unroll
            for (int d4 = 0; d4 < 16; ++d4) {
                float4 q4 = *reinterpret_cast<const float4*>(&sq[t * QPAD + d4 * 4]);
                float4 k4 = *reinterpret_cast<const float4*>(&sks[d4 * 4]);
                n = fmaf(q4.x, k4.x, n); n = fmaf(q4.y, k4.y, n);
                n = fmaf(q4.z, k4.z, n); n = fmaf(q4.w, k4.w, n);
            }
            sinv[t] = 1.0f / fmaxf(n, 1e-6f);
        }
        __syncthreads();

        float o[4][4] = {};
        #pragma unroll 16
        for (int d = 0; d < DIM; ++d) {
            const float qd = sq[sr * QPAD + d];          // 2-way max, free
            #pragma unroll
            for (int i = 0; i < 4; ++i) {
                float4 kv4 = *reinterpret_cast<const float4*>(
                    &skv[d * DIM + i * 16 + te * 4]);    // 4 addrs, 16-way bcast
                o[i][0] = fmaf(qd, kv4.x, o[i][0]);
                o[i][1] = fmaf(qd, kv4.y, o[i][1]);
                o[i][2] = fmaf(qd, kv4.z, o[i][2]);
                o[i][3] = fmaf(qd, kv4.w, o[i][3]);
            }
        }
        const float inv = sinv[sr];
        #pragma unroll
        for (int i = 0; i < 4; ++i) {
            float4 r;
            r.x = o[i][0] * inv; r.y = o[i][1] * inv;
            r.z = o[i][2] * inv; r.w = o[i][3] * inv;
            *reinterpret_cast<float4*>(&Ob[(rb + sr) * DIM + i * 16 + te * 4]) = r;
        }
    }
}

extern "C" void kernel_launch(void* const* d_in, const int* in_sizes, int n_in,
                              void* d_out, int out_size, void* d_ws, size_t ws_size,
                              hipStream_t stream) {
    const float* Q = (const float*)d_in[0];
    const float* K = (const float*)d_in[1];
    const float* V = (const float*)d_in[2];
    float* out = (float*)d_out;
    float* ws = (float*)d_ws;

    // ws is poisoned 0xAA before every timed launch: zero the kv accumulators.
    hipMemsetAsync(ws, 0, (size_t)NBH * KV_STRIDE * sizeof(float), stream);

    la_kv<<<NBH * NSPLIT, 256, 0, stream>>>(K, V, ws);
    la_out<<<NBH * NSPLIT, 256, 0, stream>>>(Q, ws, out);
}